// Round 6
// baseline (622.828 us; speedup 1.0000x reference)
//
#include <hip/hip_runtime.h>

using f16 = _Float16;
typedef __attribute__((ext_vector_type(4))) _Float16 f16x4;
typedef __attribute__((ext_vector_type(8))) _Float16 f16x8;
typedef __attribute__((ext_vector_type(4))) float f32x4;

#define DEVI __device__ __forceinline__

namespace {

constexpr int BB = 4;
constexpr int NN = 8192;
constexpr int DD = 1024;
constexpr int MTOT = BB * NN;              // 32768 rows
constexpr float FSCALE = 64.0f;            // anti-fp16-denormal scale on qf/kf
// y = acc' / (csdot' + Sq*Sk*N*eps), Sq=Sk=64, N=8192, eps=1e-6
constexpr float ZCONST = 64.0f * 64.0f * (8192.0f * 1e-6f);  // 33.554432

// async global->LDS, 16B per lane; LDS dest must be wave-uniform base
DEVI void gl16(const void* g, void* l) {
  __builtin_amdgcn_global_load_lds(
      (__attribute__((address_space(1))) void*)(void*)g,
      (__attribute__((address_space(3))) void*)l, 16, 0, 0);
}

DEVI float wsum(float v) {
#pragma unroll
  for (int m = 32; m > 0; m >>= 1) v += __shfl_xor(v, m, 64);
  return v;
}
DEVI float wmaxr(float v) {
#pragma unroll
  for (int m = 32; m > 0; m >>= 1) v = fmaxf(v, __shfl_xor(v, m, 64));
  return v;
}
DEVI float block_sum(float v, float* sred, int tid) {
  v = wsum(v);
  __syncthreads();               // protect previous use of sred
  if ((tid & 63) == 0) sred[tid >> 6] = v;
  __syncthreads();
  return sred[0] + sred[1] + sred[2] + sred[3];
}
DEVI float block_max(float v, float* sred, int tid) {
  v = wmaxr(v);
  __syncthreads();
  if ((tid & 63) == 0) sred[tid >> 6] = v;
  __syncthreads();
  return fmaxf(fmaxf(sred[0], sred[1]), fmaxf(sred[2], sred[3]));
}

// ----------------- batched fp32 -> fp16 cast (weights + kvsum only) --------
struct CastArgs {
  const float* src[8];
  f16* dst[8];
  int n4[8];
};

__global__ __launch_bounds__(256) void cast_kernel(CastArgs a) {
  const int z = blockIdx.y;
  const float4* __restrict__ s = (const float4*)a.src[z];
  f16x4* __restrict__ d = (f16x4*)a.dst[z];
  const int n4 = a.n4[z];
  for (int i = blockIdx.x * blockDim.x + threadIdx.x; i < n4;
       i += gridDim.x * blockDim.x) {
    float4 f = s[i];
    f16x4 o = {(f16)f.x, (f16)f.y, (f16)f.z, (f16)f.w};
    d[i] = o;
  }
}

// Shared GEMM geometry: C = A[M,1024] @ Bt[1024,1024]^T, BM=BN=256, BK=64,
// 8 waves (2M x 4N), 512 threads, 128 KB LDS dbuf. LDS swizzle:
// phys_chunk = chunk ^ (row&7) (both-sides rule #21). XCD-bijective block
// swizzle. 4 phases/K-tile; MFMA quadrant q consumes ds_reads issued one
// phase EARLIER via counted lgkmcnt (T3/T4): q0|q1 issued p0, q2 p1, q3 p2.
struct Gemm3 {
  const f16* A[3];
  const f16* Bt[3];
  void* C[3];
};
struct Gemm3f {
  const float* A[3];
  const f16* Bt[3];
  f16* C[3];
};

#define GEMM_PREAMBLE()                                                      \
  constexpr int K = DD;                                                      \
  constexpr int N = DD;                                                      \
  constexpr int NKT = K / 64;                                                \
  const int nx = gridDim.x;                                                  \
  int lin = blockIdx.y * nx + blockIdx.x;                                    \
  const int cpx = (gridDim.y * nx) >> 3;                                     \
  lin = (lin & 7) * cpx + (lin >> 3);                                        \
  const size_t row0 = (size_t)(lin / nx) * 256;                              \
  const size_t col0 = (size_t)(lin % nx) * 256;                              \
  const int tid = threadIdx.x, lane = tid & 63, wv = tid >> 6;               \
  const int wm = wv >> 2, wn = wv & 3;                                       \
  const int fr = lane & 15, f7 = lane & 7, kq = lane >> 4;                   \
  const int srow = wv * 8 + (lane >> 3);                                     \
  const int ssw = (lane & 7) ^ ((lane >> 3) & 7);                            \
  const int c0e = (kq ^ f7) * 8;

#define LGKM_SB(n)                                                           \
  asm volatile("s_waitcnt lgkmcnt(" #n ")" ::: "memory");                    \
  __builtin_amdgcn_sched_barrier(0);

#define MFMA_Q(mlo, afrag, bfrag)                                            \
  __builtin_amdgcn_s_setprio(1);                                             \
  _Pragma("unroll")                                                          \
  for (int mi = mlo; mi < mlo + 4; ++mi)                                     \
    _Pragma("unroll")                                                        \
    for (int ni = 0; ni < 4; ++ni)                                           \
      acc[mi][ni] = __builtin_amdgcn_mfma_f32_16x16x32_f16(                  \
          afrag[mi], bfrag[ni], acc[mi][ni], 0, 0, 0);                       \
  __builtin_amdgcn_s_setprio(0);

// ===================== fused-cast proj GEMM: fp32 A -> f16 C ================
// A staged global->reg->cvt->LDS; A-globals for kt+2 issued at end of kt's p3
// (full K-tile of flight). B via global_load_lds.
__global__ __launch_bounds__(512, 2) void gemm256_fa(Gemm3f P) {
  GEMM_PREAMBLE()
  const int z = blockIdx.z;
  const float* __restrict__ A = P.A[z];
  const f16* __restrict__ Bt = P.Bt[z];
  f16* __restrict__ C = P.C[z];

  __shared__ __align__(16) f16 LA[2][2][8192];  // [buf][half][128*64]
  __shared__ __align__(16) f16 LB[2][2][8192];

  auto stageB = [&](int kts, int half) {
    const f16* src = Bt + (col0 + half * 128 + srow) * K + kts * 64 + ssw * 8;
    f16* dst = &LB[kts & 1][half][wv * 512];
#pragma unroll
    for (int c = 0; c < 2; ++c) gl16(src + (size_t)c * 64 * K, dst + c * 4096);
  };

  // A reg-staging: thread -> row ar (0..127) in half, logical chunks ac2,ac2+1
  const int ar = tid >> 2;
  const int ac2 = (tid & 3) * 2;
  auto loadA = [&](int kts, float4* r) {
#pragma unroll
    for (int half = 0; half < 2; ++half) {
      const float* src = A + (row0 + half * 128 + ar) * (size_t)K + kts * 64;
#pragma unroll
      for (int c = 0; c < 2; ++c) {
        r[half * 4 + 2 * c + 0] = *(const float4*)(src + (ac2 + c) * 8);
        r[half * 4 + 2 * c + 1] = *(const float4*)(src + (ac2 + c) * 8 + 4);
      }
    }
  };
  auto writeA = [&](int kts, const float4* r) {
#pragma unroll
    for (int half = 0; half < 2; ++half) {
      f16* base = &LA[kts & 1][half][ar * 64];
#pragma unroll
      for (int c = 0; c < 2; ++c) {
        const float4 lo = r[half * 4 + 2 * c], hi = r[half * 4 + 2 * c + 1];
        f16x8 o = {(f16)lo.x, (f16)lo.y, (f16)lo.z, (f16)lo.w,
                   (f16)hi.x, (f16)hi.y, (f16)hi.z, (f16)hi.w};
        *(f16x8*)&base[((ac2 + c) ^ (ar & 7)) * 8] = o;
      }
    }
  };

  f32x4 acc[8][4];
#pragma unroll
  for (int i = 0; i < 8; ++i)
#pragma unroll
    for (int j = 0; j < 4; ++j) acc[i][j] = f32x4{0.f, 0.f, 0.f, 0.f};

  // prologue: invariant entering tile 0: LA[0]=A(0); ra = A(1) in flight.
  float4 ra[8];
  loadA(0, ra);
  stageB(0, 0); stageB(0, 1);
  asm volatile("s_waitcnt vmcnt(0)" ::: "memory");
  writeA(0, ra);
  asm volatile("s_waitcnt lgkmcnt(0)" ::: "memory");
  loadA(1, ra);
  __builtin_amdgcn_s_barrier();

  for (int kt = 0; kt < NKT; ++kt) {
    const int buf = kt & 1;
    const f16* Ah = LA[buf][wm];
    const f16* Bh = &LB[buf][wn >> 1][(wn & 1) * 4096];
    f16x8 a0[8], a1[8], b0[4], b1[4];

    // p0: issue q0 (a0[0-3],b0) then q1 (a0[4-7]); stage B(kt+1,0)
#pragma unroll
    for (int mi = 0; mi < 4; ++mi)
      a0[mi] = *(const f16x8*)&Ah[(mi * 16 + fr) * 64 + c0e];
#pragma unroll
    for (int ni = 0; ni < 4; ++ni)
      b0[ni] = *(const f16x8*)&Bh[(ni * 16 + fr) * 64 + c0e];
#pragma unroll
    for (int mi = 4; mi < 8; ++mi)
      a0[mi] = *(const f16x8*)&Ah[(mi * 16 + fr) * 64 + c0e];
    if (kt + 1 < NKT) stageB(kt + 1, 0);
    __builtin_amdgcn_s_barrier();
    LGKM_SB(4)                       // q0 ready; q1's 4 still in flight
    MFMA_Q(0, a0, b0)
    __builtin_amdgcn_s_barrier();

    // p1: issue q2 (a1[0-3],b1); stage B(kt+1,1)
#pragma unroll
    for (int mi = 0; mi < 4; ++mi)
      a1[mi] = *(const f16x8*)&Ah[(mi * 16 + fr) * 64 + (c0e ^ 32)];
#pragma unroll
    for (int ni = 0; ni < 4; ++ni)
      b1[ni] = *(const f16x8*)&Bh[(ni * 16 + fr) * 64 + (c0e ^ 32)];
    if (kt + 1 < NKT) stageB(kt + 1, 1);
    __builtin_amdgcn_s_barrier();
    LGKM_SB(8)                       // q1 ready; q2's 8 in flight
    MFMA_Q(4, a0, b0)
    __builtin_amdgcn_s_barrier();

    // p2: issue q3 (a1[4-7])
#pragma unroll
    for (int mi = 4; mi < 8; ++mi)
      a1[mi] = *(const f16x8*)&Ah[(mi * 16 + fr) * 64 + (c0e ^ 32)];
    __builtin_amdgcn_s_barrier();
    LGKM_SB(4)                       // q2 ready; q3's 4 in flight
    MFMA_Q(0, a1, b1)
    __builtin_amdgcn_s_barrier();

    // p3: MFMA q3; vmcnt(0); cvt+ds_write A(kt+1); issue A-globals(kt+2)
    __builtin_amdgcn_s_barrier();
    LGKM_SB(0)                       // q3 ready
    MFMA_Q(4, a1, b1)
    asm volatile("s_waitcnt vmcnt(0)" ::: "memory");
    __builtin_amdgcn_sched_barrier(0);
    if (kt + 1 < NKT) {
      writeA(kt + 1, ra);
      asm volatile("s_waitcnt lgkmcnt(0)" ::: "memory");
      if (kt + 2 < NKT) loadA(kt + 2, ra);
    }
    __builtin_amdgcn_s_barrier();
  }

#pragma unroll
  for (int mi = 0; mi < 8; ++mi)
#pragma unroll
    for (int ni = 0; ni < 4; ++ni) {
      const size_t colv = col0 + wn * 64 + ni * 16 + fr;
#pragma unroll
      for (int r = 0; r < 4; ++r) {
        const size_t rowv = row0 + wm * 128 + mi * 16 + (lane >> 4) * 4 + r;
        C[rowv * N + colv] = (f16)acc[mi][ni][r];
      }
    }
}

// ===================== f16-A GEMM (final projection) ========================
template <typename OutT>
__global__ __launch_bounds__(512, 2) void gemm256(Gemm3 P) {
  GEMM_PREAMBLE()
  const int z = blockIdx.z;
  const f16* __restrict__ A = P.A[z];
  const f16* __restrict__ Bt = P.Bt[z];
  OutT* __restrict__ C = (OutT*)P.C[z];

  __shared__ __align__(16) f16 LA[2][2][8192];
  __shared__ __align__(16) f16 LB[2][2][8192];

  auto stageA = [&](int kts, int half) {
    const f16* src = A + (row0 + half * 128 + srow) * K + kts * 64 + ssw * 8;
    f16* dst = &LA[kts & 1][half][wv * 512];
#pragma unroll
    for (int c = 0; c < 2; ++c) gl16(src + (size_t)c * 64 * K, dst + c * 4096);
  };
  auto stageB = [&](int kts, int half) {
    const f16* src = Bt + (col0 + half * 128 + srow) * K + kts * 64 + ssw * 8;
    f16* dst = &LB[kts & 1][half][wv * 512];
#pragma unroll
    for (int c = 0; c < 2; ++c) gl16(src + (size_t)c * 64 * K, dst + c * 4096);
  };

  f32x4 acc[8][4];
#pragma unroll
  for (int i = 0; i < 8; ++i)
#pragma unroll
    for (int j = 0; j < 4; ++j) acc[i][j] = f32x4{0.f, 0.f, 0.f, 0.f};

  stageA(0, 0); stageA(0, 1); stageB(0, 0); stageB(0, 1);
  stageA(1, 0); stageA(1, 1);
  asm volatile("s_waitcnt vmcnt(4)" ::: "memory");
  __builtin_amdgcn_s_barrier();

  for (int kt = 0; kt < NKT; ++kt) {
    const int buf = kt & 1;
    const f16* Ah = LA[buf][wm];
    const f16* Bh = &LB[buf][wn >> 1][(wn & 1) * 4096];
    f16x8 a0[8], a1[8], b0[4], b1[4];

    // p0: issue q0 (a0[0-3],b0) then q1 (a0[4-7]); stage B(kt+1,0)
#pragma unroll
    for (int mi = 0; mi < 4; ++mi)
      a0[mi] = *(const f16x8*)&Ah[(mi * 16 + fr) * 64 + c0e];
#pragma unroll
    for (int ni = 0; ni < 4; ++ni)
      b0[ni] = *(const f16x8*)&Bh[(ni * 16 + fr) * 64 + c0e];
#pragma unroll
    for (int mi = 4; mi < 8; ++mi)
      a0[mi] = *(const f16x8*)&Ah[(mi * 16 + fr) * 64 + c0e];
    if (kt < NKT - 1) stageB(kt + 1, 0);
    __builtin_amdgcn_s_barrier();
    LGKM_SB(4)
    MFMA_Q(0, a0, b0)
    __builtin_amdgcn_s_barrier();

    // p1: issue q2 (a1[0-3],b1); stage B(kt+1,1)
#pragma unroll
    for (int mi = 0; mi < 4; ++mi)
      a1[mi] = *(const f16x8*)&Ah[(mi * 16 + fr) * 64 + (c0e ^ 32)];
#pragma unroll
    for (int ni = 0; ni < 4; ++ni)
      b1[ni] = *(const f16x8*)&Bh[(ni * 16 + fr) * 64 + (c0e ^ 32)];
    if (kt < NKT - 1) stageB(kt + 1, 1);
    __builtin_amdgcn_s_barrier();
    LGKM_SB(8)
    MFMA_Q(4, a0, b0)
    __builtin_amdgcn_s_barrier();

    // p2: issue q3 (a1[4-7]); stage A(kt+2,0)
#pragma unroll
    for (int mi = 4; mi < 8; ++mi)
      a1[mi] = *(const f16x8*)&Ah[(mi * 16 + fr) * 64 + (c0e ^ 32)];
    if (kt < NKT - 2) stageA(kt + 2, 0);
    __builtin_amdgcn_s_barrier();
    LGKM_SB(4)
    MFMA_Q(0, a1, b1)
    __builtin_amdgcn_s_barrier();

    // p3: stage A(kt+2,1); MFMA q3; counted vmcnt
    if (kt < NKT - 2) stageA(kt + 2, 1);
    __builtin_amdgcn_s_barrier();
    LGKM_SB(0)
    MFMA_Q(4, a1, b1)
    if (kt < NKT - 2)
      asm volatile("s_waitcnt vmcnt(4)" ::: "memory");
    else
      asm volatile("s_waitcnt vmcnt(0)" ::: "memory");
    __builtin_amdgcn_s_barrier();
  }

#pragma unroll
  for (int mi = 0; mi < 8; ++mi)
#pragma unroll
    for (int ni = 0; ni < 4; ++ni) {
      const size_t colv = col0 + wn * 64 + ni * 16 + fr;
#pragma unroll
      for (int r = 0; r < 4; ++r) {
        const size_t rowv = row0 + wm * 128 + mi * 16 + (lane >> 4) * 4 + r;
        C[rowv * N + colv] = (OutT)acc[mi][ni][r];
      }
    }
}

// ----------------- feature map: |gelu|+eps, focused softmax * mean ---------
__global__ __launch_bounds__(256) void feature_kernel(
    const f16* __restrict__ qp, const f16* __restrict__ kp,
    f16* __restrict__ qf, f16* __restrict__ kf, const float* __restrict__ ffp) {
  const int row = blockIdx.x;          // 0..MTOT-1
  const int tid = threadIdx.x;
  const bool isq = (blockIdx.y == 0);
  const f16* __restrict__ src = isq ? qp : kp;
  f16* __restrict__ dst = isq ? qf : kf;
  const float ff = ffp[0];
  __shared__ float sred[4];

  f16x4 xv = ((const f16x4*)src)[(size_t)row * 256 + tid];
  float f0[4];
  float ps = 0.f;
#pragma unroll
  for (int j = 0; j < 4; ++j) {
    float x = (float)xv[j];
    float g = 0.5f * x * (1.0f + erff(x * 0.70710678118654752f));  // exact gelu
    float fv = fabsf(g) + 1e-6f;
    f0[j] = fv;
    ps += fv;
  }
  float fsum = block_sum(ps, sred, tid);
  float t[4];
  float pm = -1e30f;
#pragma unroll
  for (int j = 0; j < 4; ++j) {
    t[j] = ff * __logf(f0[j]);
    pm = fmaxf(pm, t[j]);
  }
  float tmax = block_max(pm, sred, tid);
  float e[4];
  float es = 0.f;
#pragma unroll
  for (int j = 0; j < 4; ++j) {
    e[j] = __expf(t[j] - tmax);
    es += e[j];
  }
  float esum = block_sum(es, sred, tid);
  const float scale = fsum * (1.0f / 1024.0f) / esum * FSCALE;
  f16x4 o;
#pragma unroll
  for (int j = 0; j < 4; ++j) o[j] = (f16)(e[j] * scale);
  ((f16x4*)dst)[(size_t)row * 256 + tid] = o;
}

// ----------------- kv = sum_n kh[n,c] vh[n,d]  (+ colsum over n) -----------
__global__ __launch_bounds__(256) void kv_kernel(
    const f16* __restrict__ kf, const f16* __restrict__ vp,
    float* __restrict__ kvsum, float* __restrict__ colsum) {
  const int bh = blockIdx.x;  // 0..63
  const int b = bh >> 4, h = bh & 15;
  const int tid = threadIdx.x, lane = tid & 63, wave = tid >> 6;
  __shared__ __align__(16) f16 kt[32 * 64];
  __shared__ __align__(16) f16 vt[32 * 64];
  __shared__ float csred[4][64];

  f32x4 acc[4];
#pragma unroll
  for (int ni = 0; ni < 4; ++ni) acc[ni] = f32x4{0.f, 0.f, 0.f, 0.f};
  float cpart = 0.f;

  const int srow = wave * 8 + (lane >> 3);
  const int scol = (lane & 7) * 8;
  const int colbase = h * 64;
  const int n0base = blockIdx.y * 512;

  for (int n0 = n0base; n0 < n0base + 512; n0 += 32) {
    const size_t gofs = ((size_t)(b * NN + n0 + srow)) * DD + colbase + scol;
    gl16(kf + gofs, &kt[wave * 512]);
    gl16(vp + gofs, &vt[wave * 512]);
    __syncthreads();
    {
      const int c = tid & 63;
      const int r0 = (tid >> 6) * 8;
#pragma unroll
      for (int rr = 0; rr < 8; ++rr) cpart += (float)kt[(r0 + rr) * 64 + c];
    }
    f16x8 a, bfr[4];
#pragma unroll
    for (int j = 0; j < 8; ++j)
      a[j] = kt[((lane >> 4) * 8 + j) * 64 + wave * 16 + (lane & 15)];
#pragma unroll
    for (int ni = 0; ni < 4; ++ni)
#pragma unroll
      for (int j = 0; j < 8; ++j)
        bfr[ni][j] = vt[((lane >> 4) * 8 + j) * 64 + ni * 16 + (lane & 15)];
#pragma unroll
    for (int ni = 0; ni < 4; ++ni)
      acc[ni] = __builtin_amdgcn_mfma_f32_16x16x32_f16(a, bfr[ni], acc[ni], 0, 0, 0);
    __syncthreads();
  }
#pragma unroll
  for (int ni = 0; ni < 4; ++ni)
#pragma unroll
    for (int r = 0; r < 4; ++r) {
      const int c = wave * 16 + (lane >> 4) * 4 + r;
      const int d = ni * 16 + (lane & 15);
      atomicAdd(&kvsum[(size_t)bh * 4096 + c * 64 + d], acc[ni][r]);
    }
  csred[tid >> 6][tid & 63] = cpart;
  __syncthreads();
  if (tid < 64)
    atomicAdd(&colsum[bh * 64 + tid],
              csred[0][tid] + csred[1][tid] + csred[2][tid] + csred[3][tid]);
}

// ----------------- y = (qh @ kvsum') / (qh . colsum' + ZCONST) -------------
__global__ __launch_bounds__(256) void y_kernel(
    const f16* __restrict__ qf, const f16* __restrict__ kv16,
    const float* __restrict__ colsum, f16* __restrict__ y) {
  const int bh = blockIdx.x, b = bh >> 4, h = bh & 15;
  const int n0 = blockIdx.y * 128;
  const int tid = threadIdx.x, lane = tid & 63, wave = tid >> 6;
  __shared__ __align__(16) f16 qs[128 * 64];
  __shared__ __align__(16) f16 kvs[64 * 64];
  __shared__ float cs[64];
  __shared__ float zr[128];

#pragma unroll
  for (int cc = 0; cc < 4; ++cc) {
    const int r = wave * 32 + cc * 8 + (lane >> 3);
    gl16(qf + ((size_t)(b * NN + n0 + r)) * DD + h * 64 + (lane & 7) * 8,
         &qs[(wave * 4 + cc) * 512]);
  }
#pragma unroll
  for (int cc = 0; cc < 2; ++cc) {
    const int r = wave * 16 + cc * 8 + (lane >> 3);
    gl16(kv16 + (size_t)bh * 4096 + r * 64 + (lane & 7) * 8,
         &kvs[(wave * 2 + cc) * 512]);
  }
  if (tid < 64) cs[tid] = colsum[bh * 64 + tid];
  __syncthreads();
  if (tid < 128) {
    float zv = 0.f;
    for (int cc = 0; cc < 64; ++cc) {
      const int c = (cc + tid) & 63;
      zv += (float)qs[tid * 64 + c] * cs[c];
    }
    zr[tid] = zv + ZCONST;
  }
  __syncthreads();

  f32x4 acc[2][4];
#pragma unroll
  for (int mi = 0; mi < 2; ++mi)
#pragma unroll
    for (int ni = 0; ni < 4; ++ni) acc[mi][ni] = f32x4{0.f, 0.f, 0.f, 0.f};

#pragma unroll
  for (int ks = 0; ks < 2; ++ks) {
    f16x8 a[2], bfr[4];
#pragma unroll
    for (int mi = 0; mi < 2; ++mi)
      a[mi] = *(const f16x8*)&qs[(wave * 32 + mi * 16 + (lane & 15)) * 64 +
                                 ks * 32 + (lane >> 4) * 8];
#pragma unroll
    for (int ni = 0; ni < 4; ++ni)
#pragma unroll
      for (int j = 0; j < 8; ++j)
        bfr[ni][j] = kvs[(ks * 32 + (lane >> 4) * 8 + j) * 64 + ni * 16 + (lane & 15)];
#pragma unroll
    for (int mi = 0; mi < 2; ++mi)
#pragma unroll
      for (int ni = 0; ni < 4; ++ni)
        acc[mi][ni] = __builtin_amdgcn_mfma_f32_16x16x32_f16(
            a[mi], bfr[ni], acc[mi][ni], 0, 0, 0);
  }
#pragma unroll
  for (int mi = 0; mi < 2; ++mi)
#pragma unroll
    for (int ni = 0; ni < 4; ++ni)
#pragma unroll
      for (int r = 0; r < 4; ++r) {
        const int rrow = wave * 32 + mi * 16 + (lane >> 4) * 4 + r;
        const int d = ni * 16 + (lane & 15);
        const float yv = acc[mi][ni][r] / zr[rrow];
        y[((size_t)(b * NN + n0 + rrow)) * DD + h * 64 + d] = (f16)yv;
      }
}

}  // namespace

extern "C" void kernel_launch(void* const* d_in, const int* in_sizes, int n_in,
                              void* d_out, int out_size, void* d_ws, size_t ws_size,
                              hipStream_t stream) {
  const float* q = (const float*)d_in[0];
  const float* k = (const float*)d_in[1];
  const float* v = (const float*)d_in[2];
  const float* Wq = (const float*)d_in[3];
  const float* Wk = (const float*)d_in[4];
  const float* Wv = (const float*)d_in[5];
  const float* Wp = (const float*)d_in[6];
  const float* ffp = (const float*)d_in[7];

  char* w = (char*)d_ws;
  size_t off = 0;
  auto alloc = [&](size_t b) {
    void* p = (void*)(w + off);
    off += (b + 255) & ~(size_t)255;
    return p;
  };
  const size_t big = (size_t)MTOT * DD * sizeof(f16);  // 64 MB
  f16* qp16 = (f16*)alloc(big);
  f16* kp16 = (f16*)alloc(big);
  f16* vp16 = (f16*)alloc(big);
  f16* qf  = (f16*)alloc(big);
  f16* kf  = (f16*)alloc(big);
  f16* y16 = (f16*)alloc(big);
  f16* Wq16 = (f16*)alloc((size_t)DD * DD * 2);
  f16* Wk16 = (f16*)alloc((size_t)DD * DD * 2);
  f16* Wv16 = (f16*)alloc((size_t)DD * DD * 2);
  f16* Wp16 = (f16*)alloc((size_t)DD * DD * 2);
  float* kvsum = (float*)alloc(64 * 64 * 64 * sizeof(float));   // 1 MB
  float* colsum = (float*)alloc(64 * 64 * sizeof(float));       // 16 KB
  f16* kv16 = (f16*)alloc(64 * 64 * 64 * sizeof(f16));
  if (off > ws_size) return;  // workspace too small -> fail loudly

  // 1) weight fp32 -> fp16 casts (small)
  CastArgs ca{};
  ca.src[0] = Wq; ca.dst[0] = Wq16; ca.n4[0] = DD * DD / 4;
  ca.src[1] = Wk; ca.dst[1] = Wk16; ca.n4[1] = DD * DD / 4;
  ca.src[2] = Wv; ca.dst[2] = Wv16; ca.n4[2] = DD * DD / 4;
  ca.src[3] = Wp; ca.dst[3] = Wp16; ca.n4[3] = DD * DD / 4;
  cast_kernel<<<dim3(128, 4), 256, 0, stream>>>(ca);

  // 2) projections: {q,k,v} @ W^T -> fp16, fused fp32->f16 A-cast in staging
  Gemm3f gp{};
  gp.A[0] = q; gp.Bt[0] = Wq16; gp.C[0] = qp16;
  gp.A[1] = k; gp.Bt[1] = Wk16; gp.C[1] = kp16;
  gp.A[2] = v; gp.Bt[2] = Wv16; gp.C[2] = vp16;
  gemm256_fa<<<dim3(DD / 256, MTOT / 256, 3), 512, 0, stream>>>(gp);

  // 3) feature map (softmax over full D) -> qf, kf (scaled by 64)
  feature_kernel<<<dim3(MTOT, 2), 256, 0, stream>>>(qp16, kp16, qf, kf, ffp);

  // 4) kv + colsum accumulation (fp32 atomics)
  hipMemsetAsync(kvsum, 0, 64 * 64 * 64 * sizeof(float) + 64 * 64 * sizeof(float),
                 stream);
  kv_kernel<<<dim3(64, 16), 256, 0, stream>>>(kf, vp16, kvsum, colsum);

  // 5) kvsum -> fp16
  CastArgs cb{};
  cb.src[0] = kvsum; cb.dst[0] = kv16; cb.n4[0] = 64 * 64 * 64 / 4;
  cast_kernel<<<dim3(64, 1), 256, 0, stream>>>(cb);

  // 6) y = (qh @ kv) / z, written back to [B,N,D] layout in fp16
  y_kernel<<<dim3(64, 64), 256, 0, stream>>>(qf, kv16, colsum, y16);

  // 7) out = y @ Wproj^T -> fp32 d_out
  Gemm3 gf{};
  gf.A[0] = y16; gf.Bt[0] = Wp16; gf.C[0] = d_out;
  gemm256<float><<<dim3(DD / 256, MTOT / 256, 1), 512, 0, stream>>>(gf);
}

// Round 7
// 585.719 us; speedup vs baseline: 1.0634x; 1.0634x over previous
//
#include <hip/hip_runtime.h>

using f16 = _Float16;
typedef __attribute__((ext_vector_type(4))) _Float16 f16x4;
typedef __attribute__((ext_vector_type(8))) _Float16 f16x8;
typedef __attribute__((ext_vector_type(4))) float f32x4;

#define DEVI __device__ __forceinline__

namespace {

constexpr int BB = 4;
constexpr int NN = 8192;
constexpr int DD = 1024;
constexpr int MTOT = BB * NN;              // 32768 rows
constexpr float FSCALE = 64.0f;            // anti-fp16-denormal scale on qf/kf
// y = acc' / (csdot' + Sq*Sk*N*eps), Sq=Sk=64, N=8192, eps=1e-6
constexpr float ZCONST = 64.0f * 64.0f * (8192.0f * 1e-6f);  // 33.554432

// async global->LDS, 16B per lane; LDS dest must be wave-uniform base
DEVI void gl16(const void* g, void* l) {
  __builtin_amdgcn_global_load_lds(
      (__attribute__((address_space(1))) void*)(void*)g,
      (__attribute__((address_space(3))) void*)l, 16, 0, 0);
}

DEVI float wsum(float v) {
#pragma unroll
  for (int m = 32; m > 0; m >>= 1) v += __shfl_xor(v, m, 64);
  return v;
}

// ----------------- batched fp32 -> fp16 cast (weights + kvsum only) --------
struct CastArgs {
  const float* src[8];
  f16* dst[8];
  int n4[8];
};

__global__ __launch_bounds__(256) void cast_kernel(CastArgs a) {
  const int z = blockIdx.y;
  const float4* __restrict__ s = (const float4*)a.src[z];
  f16x4* __restrict__ d = (f16x4*)a.dst[z];
  const int n4 = a.n4[z];
  for (int i = blockIdx.x * blockDim.x + threadIdx.x; i < n4;
       i += gridDim.x * blockDim.x) {
    float4 f = s[i];
    f16x4 o = {(f16)f.x, (f16)f.y, (f16)f.z, (f16)f.w};
    d[i] = o;
  }
}

// Shared GEMM geometry: C = A[M,1024] @ Bt[1024,1024]^T, BM=BN=256, BK=64,
// 8 waves (2M x 4N), 512 threads, 128 KB LDS dbuf. LDS swizzle:
// phys_chunk = chunk ^ (row&7) (both-sides rule #21). XCD-bijective block
// swizzle. 4-phase/K-tile, drain-lgkm schedule (best measured: R2/R5;
// counted-wait variants R3/R6 both regressed ~10%).
struct Gemm3 {
  const f16* A[3];
  const f16* Bt[3];
  void* C[3];
};
struct Gemm3f {
  const float* A[3];
  const f16* Bt[3];
  f16* C[3];
};

#define GEMM_PREAMBLE()                                                      \
  constexpr int K = DD;                                                      \
  constexpr int N = DD;                                                      \
  constexpr int NKT = K / 64;                                                \
  const int nx = gridDim.x;                                                  \
  int lin = blockIdx.y * nx + blockIdx.x;                                    \
  const int cpx = (gridDim.y * nx) >> 3;                                     \
  lin = (lin & 7) * cpx + (lin >> 3);                                        \
  const size_t row0 = (size_t)(lin / nx) * 256;                              \
  const size_t col0 = (size_t)(lin % nx) * 256;                              \
  const int tid = threadIdx.x, lane = tid & 63, wv = tid >> 6;               \
  const int wm = wv >> 2, wn = wv & 3;                                       \
  const int fr = lane & 15, f7 = lane & 7, kq = lane >> 4;                   \
  const int srow = wv * 8 + (lane >> 3);                                     \
  const int ssw = (lane & 7) ^ ((lane >> 3) & 7);                            \
  const int c0e = (kq ^ f7) * 8;

// ===================== fused-cast proj GEMM: fp32 A -> f16 C ================
// A staged global->reg->cvt->LDS; A-globals for kt+2 issued at end of kt's p3
// (full K-tile of flight). B via global_load_lds.
__global__ __launch_bounds__(512, 2) void gemm256_fa(Gemm3f P) {
  GEMM_PREAMBLE()
  const int z = blockIdx.z;
  const float* __restrict__ A = P.A[z];
  const f16* __restrict__ Bt = P.Bt[z];
  f16* __restrict__ C = P.C[z];

  __shared__ __align__(16) f16 LA[2][2][8192];  // [buf][half][128*64]
  __shared__ __align__(16) f16 LB[2][2][8192];

  auto stageB = [&](int kts, int half) {
    const f16* src = Bt + (col0 + half * 128 + srow) * K + kts * 64 + ssw * 8;
    f16* dst = &LB[kts & 1][half][wv * 512];
#pragma unroll
    for (int c = 0; c < 2; ++c) gl16(src + (size_t)c * 64 * K, dst + c * 4096);
  };

  // A reg-staging: thread -> row ar (0..127) in half, logical chunks ac2,ac2+1
  const int ar = tid >> 2;
  const int ac2 = (tid & 3) * 2;
  auto loadA = [&](int kts, float4* r) {
#pragma unroll
    for (int half = 0; half < 2; ++half) {
      const float* src = A + (row0 + half * 128 + ar) * (size_t)K + kts * 64;
#pragma unroll
      for (int c = 0; c < 2; ++c) {
        r[half * 4 + 2 * c + 0] = *(const float4*)(src + (ac2 + c) * 8);
        r[half * 4 + 2 * c + 1] = *(const float4*)(src + (ac2 + c) * 8 + 4);
      }
    }
  };
  auto writeA = [&](int kts, const float4* r) {
#pragma unroll
    for (int half = 0; half < 2; ++half) {
      f16* base = &LA[kts & 1][half][ar * 64];
#pragma unroll
      for (int c = 0; c < 2; ++c) {
        const float4 lo = r[half * 4 + 2 * c], hi = r[half * 4 + 2 * c + 1];
        f16x8 o = {(f16)lo.x, (f16)lo.y, (f16)lo.z, (f16)lo.w,
                   (f16)hi.x, (f16)hi.y, (f16)hi.z, (f16)hi.w};
        *(f16x8*)&base[((ac2 + c) ^ (ar & 7)) * 8] = o;
      }
    }
  };

  f32x4 acc[8][4];
#pragma unroll
  for (int i = 0; i < 8; ++i)
#pragma unroll
    for (int j = 0; j < 4; ++j) acc[i][j] = f32x4{0.f, 0.f, 0.f, 0.f};

  // prologue: invariant entering tile 0: LA[0]=A(0); ra = A(1) in flight.
  float4 ra[8];
  loadA(0, ra);
  stageB(0, 0); stageB(0, 1);
  asm volatile("s_waitcnt vmcnt(0)" ::: "memory");
  writeA(0, ra);
  asm volatile("s_waitcnt lgkmcnt(0)" ::: "memory");
  loadA(1, ra);
  __builtin_amdgcn_s_barrier();

  for (int kt = 0; kt < NKT; ++kt) {
    const int buf = kt & 1;
    const f16* Ah = LA[buf][wm];
    const f16* Bh = &LB[buf][wn >> 1][(wn & 1) * 4096];
    f16x8 a0[8], a1[8], b0[4], b1[4];

    // p0: reads a0,b0; stage B(kt+1,0); MFMA mi0-3 ks0
#pragma unroll
    for (int mi = 0; mi < 8; ++mi)
      a0[mi] = *(const f16x8*)&Ah[(mi * 16 + fr) * 64 + c0e];
#pragma unroll
    for (int ni = 0; ni < 4; ++ni)
      b0[ni] = *(const f16x8*)&Bh[(ni * 16 + fr) * 64 + c0e];
    if (kt + 1 < NKT) stageB(kt + 1, 0);
    __builtin_amdgcn_s_barrier();
    asm volatile("s_waitcnt lgkmcnt(0)" ::: "memory");
    __builtin_amdgcn_sched_barrier(0);
    __builtin_amdgcn_s_setprio(1);
#pragma unroll
    for (int mi = 0; mi < 4; ++mi)
#pragma unroll
      for (int ni = 0; ni < 4; ++ni)
        acc[mi][ni] = __builtin_amdgcn_mfma_f32_16x16x32_f16(
            a0[mi], b0[ni], acc[mi][ni], 0, 0, 0);
    __builtin_amdgcn_s_setprio(0);
    __builtin_amdgcn_s_barrier();

    // p1: reads a1; stage B(kt+1,1); MFMA mi4-7 ks0
#pragma unroll
    for (int mi = 0; mi < 8; ++mi)
      a1[mi] = *(const f16x8*)&Ah[(mi * 16 + fr) * 64 + (c0e ^ 32)];
    if (kt + 1 < NKT) stageB(kt + 1, 1);
    __builtin_amdgcn_s_barrier();
    asm volatile("s_waitcnt lgkmcnt(0)" ::: "memory");
    __builtin_amdgcn_sched_barrier(0);
    __builtin_amdgcn_s_setprio(1);
#pragma unroll
    for (int mi = 4; mi < 8; ++mi)
#pragma unroll
      for (int ni = 0; ni < 4; ++ni)
        acc[mi][ni] = __builtin_amdgcn_mfma_f32_16x16x32_f16(
            a0[mi], b0[ni], acc[mi][ni], 0, 0, 0);
    __builtin_amdgcn_s_setprio(0);
    __builtin_amdgcn_s_barrier();

    // p2: reads b1; MFMA mi0-3 ks1
#pragma unroll
    for (int ni = 0; ni < 4; ++ni)
      b1[ni] = *(const f16x8*)&Bh[(ni * 16 + fr) * 64 + (c0e ^ 32)];
    __builtin_amdgcn_s_barrier();
    asm volatile("s_waitcnt lgkmcnt(0)" ::: "memory");
    __builtin_amdgcn_sched_barrier(0);
    __builtin_amdgcn_s_setprio(1);
#pragma unroll
    for (int mi = 0; mi < 4; ++mi)
#pragma unroll
      for (int ni = 0; ni < 4; ++ni)
        acc[mi][ni] = __builtin_amdgcn_mfma_f32_16x16x32_f16(
            a1[mi], b1[ni], acc[mi][ni], 0, 0, 0);
    __builtin_amdgcn_s_setprio(0);
    __builtin_amdgcn_s_barrier();

    // p3: MFMA mi4-7 ks1; vmcnt(0) [cheap: A(kt+1) issued a full tile ago];
    //     cvt+ds_write A(kt+1); lgkm(0); issue A-globals(kt+2); barrier
    __builtin_amdgcn_s_setprio(1);
#pragma unroll
    for (int mi = 4; mi < 8; ++mi)
#pragma unroll
      for (int ni = 0; ni < 4; ++ni)
        acc[mi][ni] = __builtin_amdgcn_mfma_f32_16x16x32_f16(
            a1[mi], b1[ni], acc[mi][ni], 0, 0, 0);
    __builtin_amdgcn_s_setprio(0);
    asm volatile("s_waitcnt vmcnt(0)" ::: "memory");
    __builtin_amdgcn_sched_barrier(0);
    if (kt + 1 < NKT) {
      writeA(kt + 1, ra);
      asm volatile("s_waitcnt lgkmcnt(0)" ::: "memory");
      if (kt + 2 < NKT) loadA(kt + 2, ra);
    }
    __builtin_amdgcn_s_barrier();
  }

#pragma unroll
  for (int mi = 0; mi < 8; ++mi)
#pragma unroll
    for (int ni = 0; ni < 4; ++ni) {
      const size_t colv = col0 + wn * 64 + ni * 16 + fr;
#pragma unroll
      for (int r = 0; r < 4; ++r) {
        const size_t rowv = row0 + wm * 128 + mi * 16 + (lane >> 4) * 4 + r;
        C[rowv * N + colv] = (f16)acc[mi][ni][r];
      }
    }
}

// ===================== f16-A GEMM (final projection) ========================
template <typename OutT>
__global__ __launch_bounds__(512, 2) void gemm256(Gemm3 P) {
  GEMM_PREAMBLE()
  const int z = blockIdx.z;
  const f16* __restrict__ A = P.A[z];
  const f16* __restrict__ Bt = P.Bt[z];
  OutT* __restrict__ C = (OutT*)P.C[z];

  __shared__ __align__(16) f16 LA[2][2][8192];
  __shared__ __align__(16) f16 LB[2][2][8192];

  auto stageA = [&](int kts, int half) {
    const f16* src = A + (row0 + half * 128 + srow) * K + kts * 64 + ssw * 8;
    f16* dst = &LA[kts & 1][half][wv * 512];
#pragma unroll
    for (int c = 0; c < 2; ++c) gl16(src + (size_t)c * 64 * K, dst + c * 4096);
  };
  auto stageB = [&](int kts, int half) {
    const f16* src = Bt + (col0 + half * 128 + srow) * K + kts * 64 + ssw * 8;
    f16* dst = &LB[kts & 1][half][wv * 512];
#pragma unroll
    for (int c = 0; c < 2; ++c) gl16(src + (size_t)c * 64 * K, dst + c * 4096);
  };

  f32x4 acc[8][4];
#pragma unroll
  for (int i = 0; i < 8; ++i)
#pragma unroll
    for (int j = 0; j < 4; ++j) acc[i][j] = f32x4{0.f, 0.f, 0.f, 0.f};

  stageA(0, 0); stageA(0, 1); stageB(0, 0); stageB(0, 1);
  stageA(1, 0); stageA(1, 1);
  asm volatile("s_waitcnt vmcnt(4)" ::: "memory");
  __builtin_amdgcn_s_barrier();

  for (int kt = 0; kt < NKT; ++kt) {
    const int buf = kt & 1;
    const f16* Ah = LA[buf][wm];
    const f16* Bh = &LB[buf][wn >> 1][(wn & 1) * 4096];
    f16x8 a0[8], a1[8], b0[4], b1[4];

    // p0
#pragma unroll
    for (int mi = 0; mi < 8; ++mi)
      a0[mi] = *(const f16x8*)&Ah[(mi * 16 + fr) * 64 + c0e];
#pragma unroll
    for (int ni = 0; ni < 4; ++ni)
      b0[ni] = *(const f16x8*)&Bh[(ni * 16 + fr) * 64 + c0e];
    if (kt < NKT - 1) stageB(kt + 1, 0);
    __builtin_amdgcn_s_barrier();
    asm volatile("s_waitcnt lgkmcnt(0)" ::: "memory");
    __builtin_amdgcn_sched_barrier(0);
    __builtin_amdgcn_s_setprio(1);
#pragma unroll
    for (int mi = 0; mi < 4; ++mi)
#pragma unroll
      for (int ni = 0; ni < 4; ++ni)
        acc[mi][ni] = __builtin_amdgcn_mfma_f32_16x16x32_f16(
            a0[mi], b0[ni], acc[mi][ni], 0, 0, 0);
    __builtin_amdgcn_s_setprio(0);
    __builtin_amdgcn_s_barrier();

    // p1
#pragma unroll
    for (int mi = 0; mi < 8; ++mi)
      a1[mi] = *(const f16x8*)&Ah[(mi * 16 + fr) * 64 + (c0e ^ 32)];
    if (kt < NKT - 1) stageB(kt + 1, 1);
    __builtin_amdgcn_s_barrier();
    asm volatile("s_waitcnt lgkmcnt(0)" ::: "memory");
    __builtin_amdgcn_sched_barrier(0);
    __builtin_amdgcn_s_setprio(1);
#pragma unroll
    for (int mi = 4; mi < 8; ++mi)
#pragma unroll
      for (int ni = 0; ni < 4; ++ni)
        acc[mi][ni] = __builtin_amdgcn_mfma_f32_16x16x32_f16(
            a0[mi], b0[ni], acc[mi][ni], 0, 0, 0);
    __builtin_amdgcn_s_setprio(0);
    __builtin_amdgcn_s_barrier();

    // p2
#pragma unroll
    for (int ni = 0; ni < 4; ++ni)
      b1[ni] = *(const f16x8*)&Bh[(ni * 16 + fr) * 64 + (c0e ^ 32)];
    if (kt < NKT - 2) stageA(kt + 2, 0);
    __builtin_amdgcn_s_barrier();
    asm volatile("s_waitcnt lgkmcnt(0)" ::: "memory");
    __builtin_amdgcn_sched_barrier(0);
    __builtin_amdgcn_s_setprio(1);
#pragma unroll
    for (int mi = 0; mi < 4; ++mi)
#pragma unroll
      for (int ni = 0; ni < 4; ++ni)
        acc[mi][ni] = __builtin_amdgcn_mfma_f32_16x16x32_f16(
            a1[mi], b1[ni], acc[mi][ni], 0, 0, 0);
    __builtin_amdgcn_s_setprio(0);
    __builtin_amdgcn_s_barrier();

    // p3
    if (kt < NKT - 2) stageA(kt + 2, 1);
    __builtin_amdgcn_s_barrier();
    __builtin_amdgcn_s_setprio(1);
#pragma unroll
    for (int mi = 4; mi < 8; ++mi)
#pragma unroll
      for (int ni = 0; ni < 4; ++ni)
        acc[mi][ni] = __builtin_amdgcn_mfma_f32_16x16x32_f16(
            a1[mi], b1[ni], acc[mi][ni], 0, 0, 0);
    __builtin_amdgcn_s_setprio(0);
    if (kt < NKT - 2)
      asm volatile("s_waitcnt vmcnt(4)" ::: "memory");
    else
      asm volatile("s_waitcnt vmcnt(0)" ::: "memory");
    __builtin_amdgcn_s_barrier();
  }

#pragma unroll
  for (int mi = 0; mi < 8; ++mi)
#pragma unroll
    for (int ni = 0; ni < 4; ++ni) {
      const size_t colv = col0 + wn * 64 + ni * 16 + fr;
#pragma unroll
      for (int r = 0; r < 4; ++r) {
        const size_t rowv = row0 + wm * 128 + mi * 16 + (lane >> 4) * 4 + r;
        C[rowv * N + colv] = (OutT)acc[mi][ni][r];
      }
    }
}

// ----------------- feature map: |gelu|+eps, focused softmax * mean ---------
// Wave-per-row: 64 lanes x 16 elems, shuffle-only reductions (no LDS/sync).
// Fast erf (Abramowitz-Stegun 7.1.26, |err| < 1.5e-7). No softmax max-sub:
// t = ff*log(f) with f in [1e-6, ~16], ff=3 -> t in [-41.4, ~8.3];
// exp(t) in [1e-18, 4e3]: no overflow, underflow benign, esum > 0 always.
__global__ __launch_bounds__(256) void feature_kernel(
    const f16* __restrict__ qp, const f16* __restrict__ kp,
    f16* __restrict__ qf, f16* __restrict__ kf, const float* __restrict__ ffp) {
  const int lane = threadIdx.x & 63;
  const size_t row = (size_t)blockIdx.x * 4 + (threadIdx.x >> 6);
  const bool isq = (blockIdx.y == 0);
  const f16* __restrict__ src = isq ? qp : kp;
  f16* __restrict__ dst = isq ? qf : kf;
  const float ff = ffp[0];

  const f16x8* p = (const f16x8*)(src + row * DD + lane * 16);
  f16x8 v0 = p[0], v1 = p[1];

  float f0[16];
  float ps = 0.f;
#pragma unroll
  for (int j = 0; j < 16; ++j) {
    const float x = (float)(j < 8 ? v0[j] : v1[j - 8]);
    // erf(x/sqrt(2)) via A&S 7.1.26 on ax = |x|/sqrt(2)
    const float ax = fabsf(x) * 0.70710678118654752f;
    const float tt = 1.0f / (1.0f + 0.3275911f * ax);
    const float poly =
        tt * (0.254829592f +
              tt * (-0.284496736f +
                    tt * (1.421413741f +
                          tt * (-1.453152027f + tt * 1.061405429f))));
    const float erfv = 1.0f - poly * __expf(-ax * ax);
    const float g = 0.5f * x * (1.0f + copysignf(erfv, x));
    const float fv = fabsf(g) + 1e-6f;
    f0[j] = fv;
    ps += fv;
  }
  const float fsum = wsum(ps);

  float e[16];
  float es = 0.f;
#pragma unroll
  for (int j = 0; j < 16; ++j) {
    e[j] = __expf(ff * __logf(f0[j]));
    es += e[j];
  }
  const float esum = wsum(es);

  const float scale = fsum * (1.0f / 1024.0f) / esum * FSCALE;
  f16x8 o0, o1;
#pragma unroll
  for (int j = 0; j < 8; ++j) {
    o0[j] = (f16)(e[j] * scale);
    o1[j] = (f16)(e[j + 8] * scale);
  }
  f16x8* q = (f16x8*)(dst + row * DD + lane * 16);
  q[0] = o0;
  q[1] = o1;
}

// ----------------- kv = sum_n kh[n,c] vh[n,d]  (+ colsum over n) -----------
__global__ __launch_bounds__(256) void kv_kernel(
    const f16* __restrict__ kf, const f16* __restrict__ vp,
    float* __restrict__ kvsum, float* __restrict__ colsum) {
  const int bh = blockIdx.x;  // 0..63
  const int b = bh >> 4, h = bh & 15;
  const int tid = threadIdx.x, lane = tid & 63, wave = tid >> 6;
  __shared__ __align__(16) f16 kt[32 * 64];
  __shared__ __align__(16) f16 vt[32 * 64];
  __shared__ float csred[4][64];

  f32x4 acc[4];
#pragma unroll
  for (int ni = 0; ni < 4; ++ni) acc[ni] = f32x4{0.f, 0.f, 0.f, 0.f};
  float cpart = 0.f;

  const int srow = wave * 8 + (lane >> 3);
  const int scol = (lane & 7) * 8;
  const int colbase = h * 64;
  const int n0base = blockIdx.y * 512;

  for (int n0 = n0base; n0 < n0base + 512; n0 += 32) {
    const size_t gofs = ((size_t)(b * NN + n0 + srow)) * DD + colbase + scol;
    gl16(kf + gofs, &kt[wave * 512]);
    gl16(vp + gofs, &vt[wave * 512]);
    __syncthreads();
    {
      const int c = tid & 63;
      const int r0 = (tid >> 6) * 8;
#pragma unroll
      for (int rr = 0; rr < 8; ++rr) cpart += (float)kt[(r0 + rr) * 64 + c];
    }
    f16x8 a, bfr[4];
#pragma unroll
    for (int j = 0; j < 8; ++j)
      a[j] = kt[((lane >> 4) * 8 + j) * 64 + wave * 16 + (lane & 15)];
#pragma unroll
    for (int ni = 0; ni < 4; ++ni)
#pragma unroll
      for (int j = 0; j < 8; ++j)
        bfr[ni][j] = vt[((lane >> 4) * 8 + j) * 64 + ni * 16 + (lane & 15)];
#pragma unroll
    for (int ni = 0; ni < 4; ++ni)
      acc[ni] = __builtin_amdgcn_mfma_f32_16x16x32_f16(a, bfr[ni], acc[ni], 0, 0, 0);
    __syncthreads();
  }
#pragma unroll
  for (int ni = 0; ni < 4; ++ni)
#pragma unroll
    for (int r = 0; r < 4; ++r) {
      const int c = wave * 16 + (lane >> 4) * 4 + r;
      const int d = ni * 16 + (lane & 15);
      atomicAdd(&kvsum[(size_t)bh * 4096 + c * 64 + d], acc[ni][r]);
    }
  csred[tid >> 6][tid & 63] = cpart;
  __syncthreads();
  if (tid < 64)
    atomicAdd(&colsum[bh * 64 + tid],
              csred[0][tid] + csred[1][tid] + csred[2][tid] + csred[3][tid]);
}

// ----------------- y = (qh @ kvsum') / (qh . colsum' + ZCONST) -------------
__global__ __launch_bounds__(256) void y_kernel(
    const f16* __restrict__ qf, const f16* __restrict__ kv16,
    const float* __restrict__ colsum, f16* __restrict__ y) {
  const int bh = blockIdx.x, b = bh >> 4, h = bh & 15;
  const int n0 = blockIdx.y * 128;
  const int tid = threadIdx.x, lane = tid & 63, wave = tid >> 6;
  __shared__ __align__(16) f16 qs[128 * 64];
  __shared__ __align__(16) f16 kvs[64 * 64];
  __shared__ float cs[64];
  __shared__ float zr[128];

#pragma unroll
  for (int cc = 0; cc < 4; ++cc) {
    const int r = wave * 32 + cc * 8 + (lane >> 3);
    gl16(qf + ((size_t)(b * NN + n0 + r)) * DD + h * 64 + (lane & 7) * 8,
         &qs[(wave * 4 + cc) * 512]);
  }
#pragma unroll
  for (int cc = 0; cc < 2; ++cc) {
    const int r = wave * 16 + cc * 8 + (lane >> 3);
    gl16(kv16 + (size_t)bh * 4096 + r * 64 + (lane & 7) * 8,
         &kvs[(wave * 2 + cc) * 512]);
  }
  if (tid < 64) cs[tid] = colsum[bh * 64 + tid];
  __syncthreads();
  if (tid < 128) {
    float zv = 0.f;
    for (int cc = 0; cc < 64; ++cc) {
      const int c = (cc + tid) & 63;
      zv += (float)qs[tid * 64 + c] * cs[c];
    }
    zr[tid] = zv + ZCONST;
  }
  __syncthreads();

  f32x4 acc[2][4];
#pragma unroll
  for (int mi = 0; mi < 2; ++mi)
#pragma unroll
    for (int ni = 0; ni < 4; ++ni) acc[mi][ni] = f32x4{0.f, 0.f, 0.f, 0.f};

#pragma unroll
  for (int ks = 0; ks < 2; ++ks) {
    f16x8 a[2], bfr[4];
#pragma unroll
    for (int mi = 0; mi < 2; ++mi)
      a[mi] = *(const f16x8*)&qs[(wave * 32 + mi * 16 + (lane & 15)) * 64 +
                                 ks * 32 + (lane >> 4) * 8];
#pragma unroll
    for (int ni = 0; ni < 4; ++ni)
#pragma unroll
      for (int j = 0; j < 8; ++j)
        bfr[ni][j] = kvs[(ks * 32 + (lane >> 4) * 8 + j) * 64 + ni * 16 + (lane & 15)];
#pragma unroll
    for (int mi = 0; mi < 2; ++mi)
#pragma unroll
      for (int ni = 0; ni < 4; ++ni)
        acc[mi][ni] = __builtin_amdgcn_mfma_f32_16x16x32_f16(
            a[mi], bfr[ni], acc[mi][ni], 0, 0, 0);
  }
#pragma unroll
  for (int mi = 0; mi < 2; ++mi)
#pragma unroll
    for (int ni = 0; ni < 4; ++ni)
#pragma unroll
      for (int r = 0; r < 4; ++r) {
        const int rrow = wave * 32 + mi * 16 + (lane >> 4) * 4 + r;
        const int d = ni * 16 + (lane & 15);
        const float yv = acc[mi][ni][r] / zr[rrow];
        y[((size_t)(b * NN + n0 + rrow)) * DD + h * 64 + d] = (f16)yv;
      }
}

}  // namespace

extern "C" void kernel_launch(void* const* d_in, const int* in_sizes, int n_in,
                              void* d_out, int out_size, void* d_ws, size_t ws_size,
                              hipStream_t stream) {
  const float* q = (const float*)d_in[0];
  const float* k = (const float*)d_in[1];
  const float* v = (const float*)d_in[2];
  const float* Wq = (const float*)d_in[3];
  const float* Wk = (const float*)d_in[4];
  const float* Wv = (const float*)d_in[5];
  const float* Wp = (const float*)d_in[6];
  const float* ffp = (const float*)d_in[7];

  char* w = (char*)d_ws;
  size_t off = 0;
  auto alloc = [&](size_t b) {
    void* p = (void*)(w + off);
    off += (b + 255) & ~(size_t)255;
    return p;
  };
  const size_t big = (size_t)MTOT * DD * sizeof(f16);  // 64 MB
  f16* qp16 = (f16*)alloc(big);
  f16* kp16 = (f16*)alloc(big);
  f16* vp16 = (f16*)alloc(big);
  f16* qf  = (f16*)alloc(big);
  f16* kf  = (f16*)alloc(big);
  f16* y16 = (f16*)alloc(big);
  f16* Wq16 = (f16*)alloc((size_t)DD * DD * 2);
  f16* Wk16 = (f16*)alloc((size_t)DD * DD * 2);
  f16* Wv16 = (f16*)alloc((size_t)DD * DD * 2);
  f16* Wp16 = (f16*)alloc((size_t)DD * DD * 2);
  float* kvsum = (float*)alloc(64 * 64 * 64 * sizeof(float));   // 1 MB
  float* colsum = (float*)alloc(64 * 64 * sizeof(float));       // 16 KB
  f16* kv16 = (f16*)alloc(64 * 64 * 64 * sizeof(f16));
  if (off > ws_size) return;  // workspace too small -> fail loudly

  // 1) weight fp32 -> fp16 casts (small)
  CastArgs ca{};
  ca.src[0] = Wq; ca.dst[0] = Wq16; ca.n4[0] = DD * DD / 4;
  ca.src[1] = Wk; ca.dst[1] = Wk16; ca.n4[1] = DD * DD / 4;
  ca.src[2] = Wv; ca.dst[2] = Wv16; ca.n4[2] = DD * DD / 4;
  ca.src[3] = Wp; ca.dst[3] = Wp16; ca.n4[3] = DD * DD / 4;
  cast_kernel<<<dim3(128, 4), 256, 0, stream>>>(ca);

  // 2) projections: {q,k,v} @ W^T -> fp16, fused fp32->f16 A-cast in staging
  Gemm3f gp{};
  gp.A[0] = q; gp.Bt[0] = Wq16; gp.C[0] = qp16;
  gp.A[1] = k; gp.Bt[1] = Wk16; gp.C[1] = kp16;
  gp.A[2] = v; gp.Bt[2] = Wv16; gp.C[2] = vp16;
  gemm256_fa<<<dim3(DD / 256, MTOT / 256, 3), 512, 0, stream>>>(gp);

  // 3) feature map (softmax over full D) -> qf, kf (scaled by 64)
  feature_kernel<<<dim3(MTOT / 4, 2), 256, 0, stream>>>(qp16, kp16, qf, kf, ffp);

  // 4) kv + colsum accumulation (fp32 atomics)
  hipMemsetAsync(kvsum, 0, 64 * 64 * 64 * sizeof(float) + 64 * 64 * sizeof(float),
                 stream);
  kv_kernel<<<dim3(64, 16), 256, 0, stream>>>(kf, vp16, kvsum, colsum);

  // 5) kvsum -> fp16
  CastArgs cb{};
  cb.src[0] = kvsum; cb.dst[0] = kv16; cb.n4[0] = 64 * 64 * 64 / 4;
  cast_kernel<<<dim3(64, 1), 256, 0, stream>>>(cb);

  // 6) y = (qh @ kv) / z, written back to [B,N,D] layout in fp16
  y_kernel<<<dim3(64, 64), 256, 0, stream>>>(qf, kv16, colsum, y16);

  // 7) out = y @ Wproj^T -> fp32 d_out
  Gemm3 gf{};
  gf.A[0] = y16; gf.Bt[0] = Wp16; gf.C[0] = d_out;
  gemm256<float><<<dim3(DD / 256, MTOT / 256, 1), 512, 0, stream>>>(gf);
}